// Round 10
// baseline (915.048 us; speedup 1.0000x reference)
//
#include <hip/hip_runtime.h>
#include <hip/hip_bf16.h>

typedef __bf16 bf16_t;
typedef bf16_t bf16x8 __attribute__((ext_vector_type(8)));
typedef float  f32x4  __attribute__((ext_vector_type(4)));
typedef unsigned long long u64;
typedef unsigned int u32;

#define MFMA16(A,B,C) __builtin_amdgcn_mfma_f32_16x16x32_bf16((A),(B),(C),0,0,0)

// NQ=16384, NK=4096, QDIM=512, KDIM=256, MID=256

static __device__ __forceinline__ u64 shfl_xor_u64(u64 x, int off) {
    unsigned lo = (unsigned)x, hi = (unsigned)(x >> 32);
    lo = __shfl_xor(lo, off);
    hi = __shfl_xor(hi, off);
    return ((u64)hi << 32) | lo;
}

// async global -> LDS, 16B per lane; lds dest is wave-uniform base + lane*16.
static __device__ __forceinline__ void gl_lds16(const bf16_t* g, void* l) {
    __builtin_amdgcn_global_load_lds(
        (const __attribute__((address_space(1))) u32*)(const void*)g,
        (__attribute__((address_space(3))) u32*)l, 16, 0, 0);
}

// ---------------------------------------------------------------------------
// C_bf16[M][256] = (A_f32[M][KA] @ W_f32[256][KA]^T + b[256]) * scale
// SWZ: store 16B chunks XOR-swizzled: chunk c of row -> c ^ (row&7) (in-row).
// ---------------------------------------------------------------------------
template<int KA, bool SWZ>
__global__ __launch_bounds__(256)
void proj_kernel(const float* __restrict__ A, const float* __restrict__ W,
                 const float* __restrict__ b, bf16_t* __restrict__ C,
                 float scale)
{
    __shared__ bf16_t Alds[64][40];
    __shared__ bf16_t Wlds[256][40];

    const int t  = threadIdx.x;
    const int w  = t >> 6, l = t & 63, lr = l & 15, lg = l >> 4;
    const int m0 = blockIdx.x * 64;

    f32x4 acc[16];
#pragma unroll
    for (int tt = 0; tt < 16; ++tt) acc[tt] = (f32x4){0.f, 0.f, 0.f, 0.f};

    const int ar  = t >> 2;
    const int ac8 = (t & 3) * 8;

    for (int kb = 0; kb < KA / 32; ++kb) {
        {
            const float* ap = A + (size_t)(m0 + ar) * KA + kb * 32 + ac8;
            float4 a0 = *(const float4*)ap;
            float4 a1 = *(const float4*)(ap + 4);
            bf16x8 av;
            av[0]=(bf16_t)a0.x; av[1]=(bf16_t)a0.y; av[2]=(bf16_t)a0.z; av[3]=(bf16_t)a0.w;
            av[4]=(bf16_t)a1.x; av[5]=(bf16_t)a1.y; av[6]=(bf16_t)a1.z; av[7]=(bf16_t)a1.w;
            *(bf16x8*)&Alds[ar][ac8] = av;
        }
#pragma unroll
        for (int c = 0; c < 4; ++c) {
            int e8 = c * 256 + t;
            int wr = e8 >> 2, wc8 = (e8 & 3) * 8;
            const float* wp = W + (size_t)wr * KA + kb * 32 + wc8;
            float4 w0 = *(const float4*)wp;
            float4 w1 = *(const float4*)(wp + 4);
            bf16x8 wv;
            wv[0]=(bf16_t)w0.x; wv[1]=(bf16_t)w0.y; wv[2]=(bf16_t)w0.z; wv[3]=(bf16_t)w0.w;
            wv[4]=(bf16_t)w1.x; wv[5]=(bf16_t)w1.y; wv[6]=(bf16_t)w1.z; wv[7]=(bf16_t)w1.w;
            *(bf16x8*)&Wlds[wr][wc8] = wv;
        }
        __syncthreads();

        bf16x8 af = *(bf16x8*)&Alds[w * 16 + lr][lg * 8];
#pragma unroll
        for (int tt = 0; tt < 16; ++tt) {
            bf16x8 bfrag = *(bf16x8*)&Wlds[tt * 16 + lr][lg * 8];
            acc[tt] = MFMA16(af, bfrag, acc[tt]);
        }
        __syncthreads();
    }

#pragma unroll
    for (int tt = 0; tt < 16; ++tt) {
        int col = tt * 16 + lr;
        float bias = b[col];
#pragma unroll
        for (int r = 0; r < 4; ++r) {
            int row = m0 + w * 16 + lg * 4 + r;
            int colS = col;
            if (SWZ) colS = (((col >> 3) ^ (row & 7)) << 3) | (col & 7);
            C[(size_t)row * 256 + colS] = (bf16_t)((acc[tt][r] + bias) * scale);
        }
    }
}

// ---------------------------------------------------------------------------
// VT[256][4096] bf16, XOR-swizzled within 64-col groups:
// VT[d][g*64 + c*8 + j] holds w*S for k = g*64 + (c^(d&7))*8 + j
// ---------------------------------------------------------------------------
__global__ __launch_bounds__(256)
void buildvt_kernel(const float* __restrict__ S, const float* __restrict__ wgt,
                    bf16_t* __restrict__ VT)
{
    int i = blockIdx.x * 256 + threadIdx.x;
    int d = i >> 12, k = i & 4095;
    int kt = (k & ~63) | (((((k >> 3) & 7) ^ (d & 7)) << 3)) | (k & 7);
    VT[i] = (bf16_t)(wgt[kt] * S[(size_t)kt * 256 + d]);
}

// ---------------------------------------------------------------------------
// Flash attention, 4 waves = (qg in {0,1}) x (dh in {0,1}):
//   each wave: QK^T + softmax for its 32 q-rows (duplicated across dh),
//   PV + acc only for its 128-d half -> acc[16] = 64 AGPRs (no spill).
// K/VT staged via global_load_lds from PRE-SWIZZLED global; LDS reads XOR.
// P written once (dh==0) to shared LDS, read by both dh waves.
// LDS 72 KB -> 2 blocks/CU = 8 waves/CU. grid (256, SPLITN), 256 thr.
// ---------------------------------------------------------------------------
template<int SPLITN>
__global__ __launch_bounds__(256, 2)
void attn_kernel(const bf16_t* __restrict__ Qb, const bf16_t* __restrict__ Kb,
                 const bf16_t* __restrict__ VT, const int* __restrict__ mask,
                 float* __restrict__ out, float* __restrict__ pacc,
                 float* __restrict__ pm, float* __restrict__ pl)
{
    __shared__ __align__(16) char Kraw[32768];  // K  [64][256] swz
    __shared__ __align__(16) char Vraw[32768];  // VT [256][64] swz
    __shared__ __align__(16) char Praw[8192];   // P  [64][64]  swz

    const int t  = threadIdx.x;
    const int w  = t >> 6, l = t & 63, lr = l & 15, lg = l >> 4;
    const int qg = w & 1, dh = w >> 1;
    const int qw = blockIdx.x * 64 + qg * 32;    // wave's first q-row
    const int half = SPLITN > 1 ? (int)blockIdx.y : 0;
    const int NT   = 64 / SPLITN;
    const int kb0  = half * NT;

    // hoist Q fragments for both 16-row subgroups (A-frag: row=lr)
    bf16x8 qf[2][8];
#pragma unroll
    for (int g = 0; g < 2; ++g) {
        const bf16_t* qrow = Qb + (size_t)(qw + g * 16 + lr) * 256;
#pragma unroll
        for (int kk = 0; kk < 8; ++kk)
            qf[g][kk] = *(const bf16x8*)(qrow + kk * 32 + lg * 8);
    }

    f32x4 acc[16];                 // [g*8 + j], d = dh*128 + j*16 + lr
#pragma unroll
    for (int i = 0; i < 16; ++i) acc[i] = (f32x4){0.f, 0.f, 0.f, 0.f};
    float mrow[2][4], lsum[2][4];
#pragma unroll
    for (int g = 0; g < 2; ++g)
#pragma unroll
        for (int r = 0; r < 4; ++r) { mrow[g][r] = -1e30f; lsum[g][r] = 0.f; }

    for (int tb = 0; tb < NT; ++tb) {
        const int kb = kb0 + tb;

        // ---- mask loads (dup across dh waves; L1/L2 absorbs)
        int4 mv[2][4];
#pragma unroll
        for (int g = 0; g < 2; ++g)
#pragma unroll
            for (int r = 0; r < 4; ++r)
                mv[g][r] = *(const int4*)(mask
                    + (size_t)(qw + g * 16 + 4 * lg + r) * 4096 + kb * 64 + lr * 4);

        // ---- async stage K tile [64][256]: wave w -> rows w*16..+15
#pragma unroll
        for (int i = 0; i < 8; ++i) {
            int row = w * 16 + i * 2 + (l >> 5);
            gl_lds16(Kb + (size_t)(kb * 64 + row) * 256 + (l & 31) * 8,
                     Kraw + (w * 16 + i * 2) * 512);
        }
        // ---- async stage VT tile [256][64]: wave w -> d = w*64..+63
#pragma unroll
        for (int i = 0; i < 8; ++i) {
            int d = w * 64 + i * 8 + (l >> 3);
            gl_lds16(VT + (size_t)d * 4096 + kb * 64 + (l & 7) * 8,
                     Vraw + (w * 64 + i * 8) * 128);
        }

        // ---- pack mask bits (bit index == kv col within tile)
        u64 mw[2][4];
#pragma unroll
        for (int g = 0; g < 2; ++g)
#pragma unroll
            for (int r = 0; r < 4; ++r) {
                unsigned n = (mv[g][r].x ? 1u : 0u) | (mv[g][r].y ? 2u : 0u)
                           | (mv[g][r].z ? 4u : 0u) | (mv[g][r].w ? 8u : 0u);
                u64 pw = (u64)n << (4 * lr);
#pragma unroll
                for (int off = 1; off < 16; off <<= 1)
                    pw |= shfl_xor_u64(pw, off);
                mw[g][r] = pw;
            }
        __syncthreads();   // barrier 1: staging visible (drains vmcnt)

        // ---- S = Q K^T for both subgroups; kf shared
        f32x4 s[2][4];
#pragma unroll
        for (int g = 0; g < 2; ++g)
#pragma unroll
            for (int tt = 0; tt < 4; ++tt) s[g][tt] = (f32x4){0.f, 0.f, 0.f, 0.f};
#pragma unroll
        for (int kk = 0; kk < 8; ++kk)
#pragma unroll
            for (int tt = 0; tt < 4; ++tt) {
                bf16x8 kf = *(bf16x8*)(Kraw + (((tt * 16 + lr) * 512
                                + (kk * 4 + lg) * 16) ^ ((lr & 7) << 4)));
                s[0][tt] = MFMA16(qf[0][kk], kf, s[0][tt]);
                s[1][tt] = MFMA16(qf[1][kk], kf, s[1][tt]);
            }

        // ---- mask (C layout: row=lg*4+r, col=tt*16+lr)
#pragma unroll
        for (int g = 0; g < 2; ++g)
#pragma unroll
            for (int tt = 0; tt < 4; ++tt)
#pragma unroll
                for (int r = 0; r < 4; ++r) {
                    bool keep = ((mw[g][r] >> (tt * 16 + lr)) & 1ull) != 0;
                    s[g][tt][r] = keep ? s[g][tt][r] : -1e30f;
                }

        // ---- block row-max
        float bmx[2][4];
#pragma unroll
        for (int g = 0; g < 2; ++g)
#pragma unroll
            for (int r = 0; r < 4; ++r)
                bmx[g][r] = fmaxf(fmaxf(s[g][0][r], s[g][1][r]),
                                  fmaxf(s[g][2][r], s[g][3][r]));
#pragma unroll
        for (int off = 1; off < 16; off <<= 1)
#pragma unroll
            for (int g = 0; g < 2; ++g)
#pragma unroll
                for (int r = 0; r < 4; ++r)
                    bmx[g][r] = fmaxf(bmx[g][r], __shfl_xor(bmx[g][r], off));

        // ---- defer-max rescale (identical decision across dh pair)
        bool need = false;
#pragma unroll
        for (int g = 0; g < 2; ++g)
#pragma unroll
            for (int r = 0; r < 4; ++r)
                need = need || (bmx[g][r] > mrow[g][r] + 8.f);
        if (__any(need)) {
#pragma unroll
            for (int g = 0; g < 2; ++g)
#pragma unroll
                for (int r = 0; r < 4; ++r) {
                    float mn = fmaxf(mrow[g][r], bmx[g][r]);
                    float fr = __expf(mrow[g][r] - mn);
                    mrow[g][r] = mn;
                    lsum[g][r] *= fr;
#pragma unroll
                    for (int j = 0; j < 8; ++j) acc[g * 8 + j][r] *= fr;
                }
        }

        // ---- P = exp(S - m); row-sum
#pragma unroll
        for (int g = 0; g < 2; ++g) {
            float rs[4];
#pragma unroll
            for (int r = 0; r < 4; ++r) {
                float sum = 0.f;
#pragma unroll
                for (int tt = 0; tt < 4; ++tt) {
                    float p = __expf(s[g][tt][r] - mrow[g][r]);
                    s[g][tt][r] = p;
                    sum += p;
                }
                rs[r] = sum;
            }
#pragma unroll
            for (int off = 1; off < 16; off <<= 1)
#pragma unroll
                for (int r = 0; r < 4; ++r)
                    rs[r] += __shfl_xor(rs[r], off);
#pragma unroll
            for (int r = 0; r < 4; ++r) lsum[g][r] += rs[r];
        }

        // ---- P tile -> shared LDS (dh==0 waves only; values identical)
        if (dh == 0) {
#pragma unroll
            for (int g = 0; g < 2; ++g)
#pragma unroll
                for (int tt = 0; tt < 4; ++tt)
#pragma unroll
                    for (int r = 0; r < 4; ++r) {
                        int prow = qg * 32 + g * 16 + lg * 4 + r;
                        *(bf16_t*)(Praw + ((prow * 128 + (tt * 16 + lr) * 2)
                                           ^ ((prow & 7) << 4))) = (bf16_t)s[g][tt][r];
                    }
        }
        __syncthreads();   // barrier 2: P visible to both dh waves

        // ---- PV on this wave's 128-d half
        bf16x8 pa[2][2];
#pragma unroll
        for (int g = 0; g < 2; ++g)
#pragma unroll
            for (int h = 0; h < 2; ++h) {
                int prow = qg * 32 + g * 16 + lr;
                pa[g][h] = *(bf16x8*)(Praw + ((prow * 128 + (h * 4 + lg) * 16)
                                              ^ ((prow & 7) << 4)));
            }
#pragma unroll
        for (int j = 0; j < 8; ++j) {
            int dt = dh * 8 + j;
#pragma unroll
            for (int h = 0; h < 2; ++h) {
                bf16x8 vf = *(bf16x8*)(Vraw + (((dt * 16 + lr) * 128
                                + (h * 4 + lg) * 16) ^ ((lr & 7) << 4)));
                acc[j]     = MFMA16(pa[0][h], vf, acc[j]);
                acc[8 + j] = MFMA16(pa[1][h], vf, acc[8 + j]);
            }
        }
        __syncthreads();   // barrier 3: all LDS reads done before next staging
    }

    if (SPLITN > 1) {
        float* pa_ = pacc + (size_t)half * 16384 * 256;
#pragma unroll
        for (int g = 0; g < 2; ++g)
#pragma unroll
            for (int r = 0; r < 4; ++r) {
                int row = qw + g * 16 + lg * 4 + r;
#pragma unroll
                for (int j = 0; j < 8; ++j)
                    pa_[(size_t)row * 256 + dh * 128 + j * 16 + lr] = acc[g * 8 + j][r];
                if (lr == 0 && dh == 0) {
                    pm[half * 16384 + row] = mrow[g][r];
                    pl[half * 16384 + row] = lsum[g][r];
                }
            }
    } else {
#pragma unroll
        for (int g = 0; g < 2; ++g)
#pragma unroll
            for (int r = 0; r < 4; ++r) {
                float inv = 1.0f / lsum[g][r];
                int row = qw + g * 16 + lg * 4 + r;
#pragma unroll
                for (int j = 0; j < 8; ++j)
                    out[(size_t)row * 256 + dh * 128 + j * 16 + lr]
                        = acc[g * 8 + j][r] * inv;
            }
    }
}

// ---------------------------------------------------------------------------
// Combine the two kv-split partials.
// ---------------------------------------------------------------------------
__global__ __launch_bounds__(256)
void combine_kernel(const float* __restrict__ pacc, const float* __restrict__ pm,
                    const float* __restrict__ pl, float* __restrict__ out)
{
    int idx = blockIdx.x * 256 + threadIdx.x;
    int row = idx >> 6, c4 = (idx & 63) * 4;
    float m0 = pm[row], m1 = pm[16384 + row];
    float l0 = pl[row], l1 = pl[16384 + row];
    float m  = fmaxf(m0, m1);
    float a  = __expf(m0 - m), b = __expf(m1 - m);
    float inv = 1.0f / (l0 * a + l1 * b);
    float4 x0 = *(const float4*)(pacc + (size_t)row * 256 + c4);
    float4 x1 = *(const float4*)(pacc + (size_t)16384 * 256 + (size_t)row * 256 + c4);
    float4 o;
    o.x = (x0.x * a + x1.x * b) * inv;
    o.y = (x0.y * a + x1.y * b) * inv;
    o.z = (x0.z * a + x1.z * b) * inv;
    o.w = (x0.w * a + x1.w * b) * inv;
    *(float4*)(out + (size_t)row * 256 + c4) = o;
}

// ---------------------------------------------------------------------------
extern "C" void kernel_launch(void* const* d_in, const int* in_sizes, int n_in,
                              void* d_out, int out_size, void* d_ws, size_t ws_size,
                              hipStream_t stream)
{
    const float* gE   = (const float*)d_in[0];
    const float* sE   = (const float*)d_in[1];
    const float* wgt  = (const float*)d_in[2];
    const int*   mask = (const int*)  d_in[3];
    const float* Wq   = (const float*)d_in[4];
    const float* bq   = (const float*)d_in[5];
    const float* Wk   = (const float*)d_in[6];
    const float* bk   = (const float*)d_in[7];
    float* out = (float*)d_out;

    char* ws = (char*)d_ws;
    bf16_t* Qb = (bf16_t*)ws;                              //  8 MB @ 0
    bf16_t* Kb = (bf16_t*)(ws + 8388608);                  //  2 MB (swizzled)
    bf16_t* VT = (bf16_t*)(ws + 10485760);                 //  2 MB (swizzled)
    float*  pacc = (float*)(ws + 12582912);                // 32 MB (2 splits)
    float*  pm   = (float*)(ws + 46137344);                // 128 KB
    float*  pl   = (float*)(ws + 46268416);                // 128 KB
    const size_t need_full = 46399488;
    const size_t need_min  = 12582912;

    if (ws_size < need_min) return;

    proj_kernel<512, false><<<dim3(256, 1), 256, 0, stream>>>(gE, Wq, bq, Qb, 0.0625f);
    proj_kernel<256, true ><<<dim3(64, 1), 256, 0, stream>>>(sE, Wk, bk, Kb, 1.0f);
    buildvt_kernel<<<4096, 256, 0, stream>>>(sE, wgt, VT);

    if (ws_size >= need_full) {
        attn_kernel<2><<<dim3(256, 2), 256, 0, stream>>>(
            Qb, Kb, VT, mask, out, pacc, pm, pl);
        combine_kernel<<<4096, 256, 0, stream>>>(pacc, pm, pl, out);
    } else {
        attn_kernel<1><<<dim3(256, 1), 256, 0, stream>>>(
            Qb, Kb, VT, mask, out, nullptr, nullptr, nullptr);
    }
}

// Round 11
// 217.856 us; speedup vs baseline: 4.2002x; 4.2002x over previous
//
#include <hip/hip_runtime.h>
#include <hip/hip_bf16.h>

typedef __bf16 bf16_t;
typedef bf16_t bf16x8 __attribute__((ext_vector_type(8)));
typedef float  f32x4  __attribute__((ext_vector_type(4)));
typedef unsigned long long u64;

#define MFMA16(A,B,C) __builtin_amdgcn_mfma_f32_16x16x32_bf16((A),(B),(C),0,0,0)

// NQ=16384, NK=4096, QDIM=512, KDIM=256, MID=256

// ---------------------------------------------------------------------------
// C_bf16[M][256] = (A_f32[M][KA] @ W_f32[256][KA]^T + b[256]) * scale
// ---------------------------------------------------------------------------
template<int KA>
__global__ __launch_bounds__(256)
void proj_kernel(const float* __restrict__ A, const float* __restrict__ W,
                 const float* __restrict__ b, bf16_t* __restrict__ C,
                 float scale)
{
    __shared__ bf16_t Alds[64][40];
    __shared__ bf16_t Wlds[256][40];

    const int t  = threadIdx.x;
    const int w  = t >> 6, l = t & 63, lr = l & 15, lg = l >> 4;
    const int m0 = blockIdx.x * 64;

    f32x4 acc[16];
#pragma unroll
    for (int tt = 0; tt < 16; ++tt) acc[tt] = (f32x4){0.f, 0.f, 0.f, 0.f};

    const int ar  = t >> 2;
    const int ac8 = (t & 3) * 8;

    for (int kb = 0; kb < KA / 32; ++kb) {
        {
            const float* ap = A + (size_t)(m0 + ar) * KA + kb * 32 + ac8;
            float4 a0 = *(const float4*)ap;
            float4 a1 = *(const float4*)(ap + 4);
            bf16x8 av;
            av[0]=(bf16_t)a0.x; av[1]=(bf16_t)a0.y; av[2]=(bf16_t)a0.z; av[3]=(bf16_t)a0.w;
            av[4]=(bf16_t)a1.x; av[5]=(bf16_t)a1.y; av[6]=(bf16_t)a1.z; av[7]=(bf16_t)a1.w;
            *(bf16x8*)&Alds[ar][ac8] = av;
        }
#pragma unroll
        for (int c = 0; c < 4; ++c) {
            int e8 = c * 256 + t;
            int wr = e8 >> 2, wc8 = (e8 & 3) * 8;
            const float* wp = W + (size_t)wr * KA + kb * 32 + wc8;
            float4 w0 = *(const float4*)wp;
            float4 w1 = *(const float4*)(wp + 4);
            bf16x8 wv;
            wv[0]=(bf16_t)w0.x; wv[1]=(bf16_t)w0.y; wv[2]=(bf16_t)w0.z; wv[3]=(bf16_t)w0.w;
            wv[4]=(bf16_t)w1.x; wv[5]=(bf16_t)w1.y; wv[6]=(bf16_t)w1.z; wv[7]=(bf16_t)w1.w;
            *(bf16x8*)&Wlds[wr][wc8] = wv;
        }
        __syncthreads();

        bf16x8 af = *(bf16x8*)&Alds[w * 16 + lr][lg * 8];
#pragma unroll
        for (int tt = 0; tt < 16; ++tt) {
            bf16x8 bfrag = *(bf16x8*)&Wlds[tt * 16 + lr][lg * 8];
            acc[tt] = MFMA16(af, bfrag, acc[tt]);
        }
        __syncthreads();
    }

#pragma unroll
    for (int tt = 0; tt < 16; ++tt) {
        int col = tt * 16 + lr;
        float bias = b[col];
#pragma unroll
        for (int r = 0; r < 4; ++r) {
            int row = m0 + w * 16 + lg * 4 + r;
            C[(size_t)row * 256 + col] = (bf16_t)((acc[tt][r] + bias) * scale);
        }
    }
}

// ---------------------------------------------------------------------------
// VT[256][4096] bf16: VT[d][k] = w[k] * S[k][d]
// ---------------------------------------------------------------------------
__global__ __launch_bounds__(256)
void buildvt_kernel(const float* __restrict__ S, const float* __restrict__ wgt,
                    bf16_t* __restrict__ VT)
{
    int i = blockIdx.x * 256 + threadIdx.x;
    int d = i >> 12, k = i & 4095;
    VT[i] = (bf16_t)(wgt[k] * S[(size_t)k * 256 + d]);
}

// ---------------------------------------------------------------------------
// Flash attention (round-5 structure) with LDS-pipe relief:
//  * mask pack via 16 __ballot (SGPR) instead of 32 ds_bpermute OR-reduce
//  * softmax denominator via ones-MFMA (rescales like acc) instead of
//    16-bpermute row-sum shuffle
// grid (256, SPLIT?2:1), 256 threads = 4 waves (16 q-rows/wave).
// ---------------------------------------------------------------------------
template<bool SPLIT>
__global__ __launch_bounds__(256, 2)
void attn_kernel(const bf16_t* __restrict__ Qb, const bf16_t* __restrict__ Kb,
                 const bf16_t* __restrict__ VT, const int* __restrict__ mask,
                 float* __restrict__ out, float* __restrict__ pacc,
                 float* __restrict__ pm, float* __restrict__ pl)
{
    __shared__ bf16_t Klds[64][264];    // 33.8 KB
    __shared__ bf16_t VTlds[256][72];   // 36.9 KB
    __shared__ bf16_t Plds[64][72];     //  9.2 KB   (79872 B -> 2 blk/CU)

    const int t  = threadIdx.x;
    const int w  = t >> 6, l = t & 63, lr = l & 15, lg = l >> 4;
    const int q0 = blockIdx.x * 64;
    const int qw = q0 + w * 16;
    const int half = SPLIT ? (int)blockIdx.y : 0;
    const int NT   = SPLIT ? 32 : 64;
    const int kb0  = half * NT;

    // hoist Q fragments (A-frag: row = lr, k = kk*32 + lg*8 + j)
    bf16x8 qf[8];
    {
        const bf16_t* qrow = Qb + (size_t)(qw + lr) * 256;
#pragma unroll
        for (int kk = 0; kk < 8; ++kk)
            qf[kk] = *(const bf16x8*)(qrow + kk * 32 + lg * 8);
    }

    bf16x8 vone;
#pragma unroll
    for (int j = 0; j < 8; ++j) vone[j] = (bf16_t)1.0f;

    f32x4 acc[16];
#pragma unroll
    for (int dt = 0; dt < 16; ++dt) acc[dt] = (f32x4){0.f, 0.f, 0.f, 0.f};
    f32x4 lacc = (f32x4){0.f, 0.f, 0.f, 0.f};   // row-sum accumulator (P @ 1)
    float mrow[4];
#pragma unroll
    for (int r = 0; r < 4; ++r) mrow[r] = -1e30f;

    for (int tb = 0; tb < NT; ++tb) {
        const int kb = kb0 + tb;

        // ---- mask loads first (hide latency under staging)
        int4 mv[4];
#pragma unroll
        for (int r = 0; r < 4; ++r)
            mv[r] = *(const int4*)(mask + (size_t)(qw + 4 * lg + r) * 4096
                                   + kb * 64 + lr * 4);

        // ---- stage K tile [64][256]
#pragma unroll
        for (int c = 0; c < 8; ++c) {
            int e8 = c * 256 + t;
            int krow = e8 >> 5, kc8 = (e8 & 31) * 8;
            *(bf16x8*)&Klds[krow][kc8] =
                *(const bf16x8*)(Kb + (size_t)(kb * 64 + krow) * 256 + kc8);
        }
        // ---- stage VT tile [256][64]
#pragma unroll
        for (int c = 0; c < 8; ++c) {
            int e8 = c * 256 + t;
            int d = e8 >> 3, c8 = (e8 & 7) * 8;
            *(bf16x8*)&VTlds[d][c8] =
                *(const bf16x8*)(VT + (size_t)d * 4096 + kb * 64 + c8);
        }

        // ---- mask via ballot: row (qw+4lg+r), col (tt*16+lr) lives at
        // ballot[lr&3] bit (lg*16 + tt*4 + (lr>>2)).  No LDS-pipe traffic.
        u64 rowbits[4];
#pragma unroll
        for (int r = 0; r < 4; ++r) {
            u64 b0 = __ballot(mv[r].x != 0);
            u64 b1 = __ballot(mv[r].y != 0);
            u64 b2 = __ballot(mv[r].z != 0);
            u64 b3 = __ballot(mv[r].w != 0);
            u64 w01  = (lr & 1) ? b1 : b0;
            u64 w23  = (lr & 1) ? b3 : b2;
            u64 wsel = (lr & 2) ? w23 : w01;
            rowbits[r] = wsel >> (lg * 16 + (lr >> 2));  // bit 4*tt = keep
        }
        __syncthreads();

        // ---- S = Q K^T (pre-scaled via Qb)
        f32x4 s[4];
#pragma unroll
        for (int tt = 0; tt < 4; ++tt) {
            f32x4 sv = (f32x4){0.f, 0.f, 0.f, 0.f};
#pragma unroll
            for (int kk = 0; kk < 8; ++kk) {
                bf16x8 kf = *(bf16x8*)&Klds[tt * 16 + lr][kk * 32 + lg * 8];
                sv = MFMA16(qf[kk], kf, sv);
            }
            s[tt] = sv;
        }
        // mask (C layout: row = lg*4+r, col = tt*16+lr)
#pragma unroll
        for (int tt = 0; tt < 4; ++tt)
#pragma unroll
            for (int r = 0; r < 4; ++r) {
                bool keep = ((rowbits[r] >> (4 * tt)) & 1ull) != 0;
                s[tt][r] = keep ? s[tt][r] : -1e30f;
            }

        // block row-max over 64 cols
        float bm[4];
#pragma unroll
        for (int r = 0; r < 4; ++r)
            bm[r] = fmaxf(fmaxf(s[0][r], s[1][r]), fmaxf(s[2][r], s[3][r]));
#pragma unroll
        for (int off = 1; off < 16; off <<= 1)
#pragma unroll
            for (int r = 0; r < 4; ++r)
                bm[r] = fmaxf(bm[r], __shfl_xor(bm[r], off));

        // defer-max: rescale only when running max grows by > 8
        bool need = false;
#pragma unroll
        for (int r = 0; r < 4; ++r) need = need || (bm[r] > mrow[r] + 8.f);
        if (__any(need)) {
#pragma unroll
            for (int r = 0; r < 4; ++r) {
                float mn = fmaxf(mrow[r], bm[r]);
                float fr = __expf(mrow[r] - mn);
                mrow[r] = mn;
                lacc[r] *= fr;
#pragma unroll
                for (int dt = 0; dt < 16; ++dt) acc[dt][r] *= fr;
            }
        }

        // ---- P = exp(S - m); write P tile (bf16) to wave-private LDS rows
#pragma unroll
        for (int tt = 0; tt < 4; ++tt)
#pragma unroll
            for (int r = 0; r < 4; ++r)
                Plds[w * 16 + lg * 4 + r][tt * 16 + lr]
                    = (bf16_t)__expf(s[tt][r] - mrow[r]);
        asm volatile("s_waitcnt lgkmcnt(0)" ::: "memory");
        __builtin_amdgcn_sched_barrier(0);

        // ---- PV (+ row-sum via ones-MFMA: lacc += P @ 1)
        bf16x8 pa0 = *(bf16x8*)&Plds[w * 16 + lr][lg * 8];
        bf16x8 pa1 = *(bf16x8*)&Plds[w * 16 + lr][32 + lg * 8];
        lacc = MFMA16(pa0, vone, lacc);
        lacc = MFMA16(pa1, vone, lacc);
#pragma unroll
        for (int dt = 0; dt < 16; ++dt) {
            bf16x8 v0 = *(bf16x8*)&VTlds[dt * 16 + lr][lg * 8];
            bf16x8 v1 = *(bf16x8*)&VTlds[dt * 16 + lr][32 + lg * 8];
            acc[dt] = MFMA16(pa0, v0, acc[dt]);
            acc[dt] = MFMA16(pa1, v1, acc[dt]);
        }
        __syncthreads();
    }

    if (SPLIT) {
        float* pa = pacc + (size_t)half * 16384 * 256;
#pragma unroll
        for (int r = 0; r < 4; ++r) {
            int row = qw + lg * 4 + r;
#pragma unroll
            for (int dt = 0; dt < 16; ++dt)
                pa[(size_t)row * 256 + dt * 16 + lr] = acc[dt][r];
            if (lr == 0) {
                pm[half * 16384 + row] = mrow[r];
                pl[half * 16384 + row] = lacc[r];
            }
        }
    } else {
#pragma unroll
        for (int r = 0; r < 4; ++r) {
            float inv = 1.0f / lacc[r];
#pragma unroll
            for (int dt = 0; dt < 16; ++dt)
                out[(size_t)(qw + lg * 4 + r) * 256 + dt * 16 + lr] = acc[dt][r] * inv;
        }
    }
}

// ---------------------------------------------------------------------------
// Combine the two kv-split partials.
// ---------------------------------------------------------------------------
__global__ __launch_bounds__(256)
void combine_kernel(const float* __restrict__ pacc, const float* __restrict__ pm,
                    const float* __restrict__ pl, float* __restrict__ out)
{
    int idx = blockIdx.x * 256 + threadIdx.x;
    int row = idx >> 6, c4 = (idx & 63) * 4;
    float m0 = pm[row], m1 = pm[16384 + row];
    float l0 = pl[row], l1 = pl[16384 + row];
    float m  = fmaxf(m0, m1);
    float a  = __expf(m0 - m), b = __expf(m1 - m);
    float inv = 1.0f / (l0 * a + l1 * b);
    float4 x0 = *(const float4*)(pacc + (size_t)row * 256 + c4);
    float4 x1 = *(const float4*)(pacc + (size_t)16384 * 256 + (size_t)row * 256 + c4);
    float4 o;
    o.x = (x0.x * a + x1.x * b) * inv;
    o.y = (x0.y * a + x1.y * b) * inv;
    o.z = (x0.z * a + x1.z * b) * inv;
    o.w = (x0.w * a + x1.w * b) * inv;
    *(float4*)(out + (size_t)row * 256 + c4) = o;
}

// ---------------------------------------------------------------------------
extern "C" void kernel_launch(void* const* d_in, const int* in_sizes, int n_in,
                              void* d_out, int out_size, void* d_ws, size_t ws_size,
                              hipStream_t stream)
{
    const float* gE   = (const float*)d_in[0];
    const float* sE   = (const float*)d_in[1];
    const float* wgt  = (const float*)d_in[2];
    const int*   mask = (const int*)  d_in[3];
    const float* Wq   = (const float*)d_in[4];
    const float* bq   = (const float*)d_in[5];
    const float* Wk   = (const float*)d_in[6];
    const float* bk   = (const float*)d_in[7];
    float* out = (float*)d_out;

    char* ws = (char*)d_ws;
    bf16_t* Qb = (bf16_t*)ws;                              //  8 MB @ 0
    bf16_t* Kb = (bf16_t*)(ws + 8388608);                  //  2 MB
    bf16_t* VT = (bf16_t*)(ws + 10485760);                 //  2 MB
    float*  pacc = (float*)(ws + 12582912);                // 32 MB (2 splits)
    float*  pm   = (float*)(ws + 46137344);                // 128 KB
    float*  pl   = (float*)(ws + 46268416);                // 128 KB
    const size_t need_full = 46399488;
    const size_t need_min  = 12582912;

    if (ws_size < need_min) return;

    proj_kernel<512><<<dim3(256, 1), 256, 0, stream>>>(gE, Wq, bq, Qb, 0.0625f);
    proj_kernel<256><<<dim3(64, 1), 256, 0, stream>>>(sE, Wk, bk, Kb, 1.0f);
    buildvt_kernel<<<4096, 256, 0, stream>>>(sE, wgt, VT);

    if (ws_size >= need_full) {
        attn_kernel<true><<<dim3(256, 2), 256, 0, stream>>>(
            Qb, Kb, VT, mask, out, pacc, pm, pl);
        combine_kernel<<<4096, 256, 0, stream>>>(pacc, pm, pl, out);
    } else {
        attn_kernel<false><<<dim3(256, 1), 256, 0, stream>>>(
            Qb, Kb, VT, mask, out, nullptr, nullptr, nullptr);
    }
}

// Round 12
// 210.534 us; speedup vs baseline: 4.3463x; 1.0348x over previous
//
#include <hip/hip_runtime.h>
#include <hip/hip_bf16.h>

typedef __bf16 bf16_t;
typedef bf16_t bf16x8 __attribute__((ext_vector_type(8)));
typedef float  f32x4  __attribute__((ext_vector_type(4)));
typedef unsigned long long u64;
typedef unsigned int u32;

#define MFMA16(A,B,C) __builtin_amdgcn_mfma_f32_16x16x32_bf16((A),(B),(C),0,0,0)

// NQ=16384, NK=4096, QDIM=512, KDIM=256, MID=256

// async global -> LDS, 16B per lane; LDS dest = wave-uniform base + lane*16.
static __device__ __forceinline__ void gl_lds16(const bf16_t* g, void* l) {
    __builtin_amdgcn_global_load_lds(
        (const __attribute__((address_space(1))) u32*)(const void*)g,
        (__attribute__((address_space(3))) u32*)l, 16, 0, 0);
}

// ---------------------------------------------------------------------------
// C_bf16[M][256] = (A_f32[M][KA] @ W_f32[256][KA]^T + b[256]) * scale
// SWZ: 16B chunk c of row stored at c ^ (row&7)  (verified r9/r10)
// ---------------------------------------------------------------------------
template<int KA, bool SWZ>
__global__ __launch_bounds__(256)
void proj_kernel(const float* __restrict__ A, const float* __restrict__ W,
                 const float* __restrict__ b, bf16_t* __restrict__ C,
                 float scale)
{
    __shared__ bf16_t Alds[64][40];
    __shared__ bf16_t Wlds[256][40];

    const int t  = threadIdx.x;
    const int w  = t >> 6, l = t & 63, lr = l & 15, lg = l >> 4;
    const int m0 = blockIdx.x * 64;

    f32x4 acc[16];
#pragma unroll
    for (int tt = 0; tt < 16; ++tt) acc[tt] = (f32x4){0.f, 0.f, 0.f, 0.f};

    const int ar  = t >> 2;
    const int ac8 = (t & 3) * 8;

    for (int kb = 0; kb < KA / 32; ++kb) {
        {
            const float* ap = A + (size_t)(m0 + ar) * KA + kb * 32 + ac8;
            float4 a0 = *(const float4*)ap;
            float4 a1 = *(const float4*)(ap + 4);
            bf16x8 av;
            av[0]=(bf16_t)a0.x; av[1]=(bf16_t)a0.y; av[2]=(bf16_t)a0.z; av[3]=(bf16_t)a0.w;
            av[4]=(bf16_t)a1.x; av[5]=(bf16_t)a1.y; av[6]=(bf16_t)a1.z; av[7]=(bf16_t)a1.w;
            *(bf16x8*)&Alds[ar][ac8] = av;
        }
#pragma unroll
        for (int c = 0; c < 4; ++c) {
            int e8 = c * 256 + t;
            int wr = e8 >> 2, wc8 = (e8 & 3) * 8;
            const float* wp = W + (size_t)wr * KA + kb * 32 + wc8;
            float4 w0 = *(const float4*)wp;
            float4 w1 = *(const float4*)(wp + 4);
            bf16x8 wv;
            wv[0]=(bf16_t)w0.x; wv[1]=(bf16_t)w0.y; wv[2]=(bf16_t)w0.z; wv[3]=(bf16_t)w0.w;
            wv[4]=(bf16_t)w1.x; wv[5]=(bf16_t)w1.y; wv[6]=(bf16_t)w1.z; wv[7]=(bf16_t)w1.w;
            *(bf16x8*)&Wlds[wr][wc8] = wv;
        }
        __syncthreads();

        bf16x8 af = *(bf16x8*)&Alds[w * 16 + lr][lg * 8];
#pragma unroll
        for (int tt = 0; tt < 16; ++tt) {
            bf16x8 bfrag = *(bf16x8*)&Wlds[tt * 16 + lr][lg * 8];
            acc[tt] = MFMA16(af, bfrag, acc[tt]);
        }
        __syncthreads();
    }

#pragma unroll
    for (int tt = 0; tt < 16; ++tt) {
        int col = tt * 16 + lr;
        float bias = b[col];
#pragma unroll
        for (int r = 0; r < 4; ++r) {
            int row = m0 + w * 16 + lg * 4 + r;
            int colS = col;
            if (SWZ) colS = (((col >> 3) ^ (row & 7)) << 3) | (col & 7);
            C[(size_t)row * 256 + colS] = (bf16_t)((acc[tt][r] + bias) * scale);
        }
    }
}

// ---------------------------------------------------------------------------
// VT[256][4096] bf16, pre-swizzled within 64-col groups (verified r9/r10):
// VT[d][g*64 + c*8 + j] holds w*S for k = g*64 + (c^(d&7))*8 + j
// ---------------------------------------------------------------------------
__global__ __launch_bounds__(256)
void buildvt_kernel(const float* __restrict__ S, const float* __restrict__ wgt,
                    bf16_t* __restrict__ VT)
{
    int i = blockIdx.x * 256 + threadIdx.x;
    int d = i >> 12, k = i & 4095;
    int kt = (k & ~63) | (((((k >> 3) & 7) ^ (d & 7)) << 3)) | (k & 7);
    VT[i] = (bf16_t)(wgt[kt] * S[(size_t)kt * 256 + d]);
}

// ---------------------------------------------------------------------------
// Flash attention (round-11 compute structure) with conflict-free staging:
//  * Kb/VT pre-swizzled in global; staged via global_load_lds (linear LDS
//    dest, 1KB/instr, no VGPR round-trip, conflict-free writes)
//  * all LDS reads XOR (row&7)<<4; P buffer swizzled the same way
//  * mask via __ballot (SGPR path); denominator via ones-MFMA
// grid (256, SPLIT?2:1), 256 threads = 4 waves (16 q-rows/wave). LDS 72KB.
// ---------------------------------------------------------------------------
template<bool SPLIT>
__global__ __launch_bounds__(256, 2)
void attn_kernel(const bf16_t* __restrict__ Qb, const bf16_t* __restrict__ Kb,
                 const bf16_t* __restrict__ VT, const int* __restrict__ mask,
                 float* __restrict__ out, float* __restrict__ pacc,
                 float* __restrict__ pm, float* __restrict__ pl)
{
    __shared__ __align__(16) char Kraw[32768];  // K  [64][256] (global pre-swz)
    __shared__ __align__(16) char Vraw[32768];  // VT [256][64] (global pre-swz)
    __shared__ __align__(16) char Praw[8192];   // P  [64][64]  swz on write/read

    const int t  = threadIdx.x;
    const int w  = t >> 6, l = t & 63, lr = l & 15, lg = l >> 4;
    const int q0 = blockIdx.x * 64;
    const int qw = q0 + w * 16;
    const int half = SPLIT ? (int)blockIdx.y : 0;
    const int NT   = SPLIT ? 32 : 64;
    const int kb0  = half * NT;

    // hoist Q fragments (A-frag: row = lr, k = kk*32 + lg*8 + j)
    bf16x8 qf[8];
    {
        const bf16_t* qrow = Qb + (size_t)(qw + lr) * 256;
#pragma unroll
        for (int kk = 0; kk < 8; ++kk)
            qf[kk] = *(const bf16x8*)(qrow + kk * 32 + lg * 8);
    }

    bf16x8 vone;
#pragma unroll
    for (int j = 0; j < 8; ++j) vone[j] = (bf16_t)1.0f;

    f32x4 acc[16];
#pragma unroll
    for (int dt = 0; dt < 16; ++dt) acc[dt] = (f32x4){0.f, 0.f, 0.f, 0.f};
    f32x4 lacc = (f32x4){0.f, 0.f, 0.f, 0.f};   // row-sum accumulator (P @ 1)
    float mrow[4];
#pragma unroll
    for (int r = 0; r < 4; ++r) mrow[r] = -1e30f;

    for (int tb = 0; tb < NT; ++tb) {
        const int kb = kb0 + tb;

        // ---- mask loads FIRST (older in vmcnt FIFO -> ballot doesn't
        //      wait on the staging loads below)
        int4 mv[4];
#pragma unroll
        for (int r = 0; r < 4; ++r)
            mv[r] = *(const int4*)(mask + (size_t)(qw + 4 * lg + r) * 4096
                                   + kb * 64 + lr * 4);

        // ---- async stage K tile [64][256]: wave w -> rows w*16..+15
        //      (2 rows = 1KB per instr; lane l covers row +(l>>5), chunk l&31)
#pragma unroll
        for (int i = 0; i < 8; ++i) {
            int row = w * 16 + i * 2 + (l >> 5);
            gl_lds16(Kb + (size_t)(kb * 64 + row) * 256 + (l & 31) * 8,
                     Kraw + (w * 16 + i * 2) * 512);
        }
        // ---- async stage VT tile [256][64]: wave w -> d = w*64..+63
#pragma unroll
        for (int i = 0; i < 8; ++i) {
            int d = w * 64 + i * 8 + (l >> 3);
            gl_lds16(VT + (size_t)d * 4096 + kb * 64 + (l & 7) * 8,
                     Vraw + (w * 64 + i * 8) * 128);
        }

        // ---- mask via ballot: row (qw+4lg+r), col (tt*16+lr) lives at
        // ballot[lr&3] bit (lg*16 + tt*4 + (lr>>2)).  SGPR path, no LDS.
        u64 rowbits[4];
#pragma unroll
        for (int r = 0; r < 4; ++r) {
            u64 b0 = __ballot(mv[r].x != 0);
            u64 b1 = __ballot(mv[r].y != 0);
            u64 b2 = __ballot(mv[r].z != 0);
            u64 b3 = __ballot(mv[r].w != 0);
            u64 w01  = (lr & 1) ? b1 : b0;
            u64 w23  = (lr & 1) ? b3 : b2;
            u64 wsel = (lr & 2) ? w23 : w01;
            rowbits[r] = wsel >> (lg * 16 + (lr >> 2));  // bit 4*tt = keep
        }
        __syncthreads();   // barrier 1: staging visible (drains vmcnt)

        // ---- S = Q K^T (pre-scaled via Qb); K row = tt*16+lr, row&7 = lr&7
        f32x4 s[4];
#pragma unroll
        for (int tt = 0; tt < 4; ++tt) {
            f32x4 sv = (f32x4){0.f, 0.f, 0.f, 0.f};
#pragma unroll
            for (int kk = 0; kk < 8; ++kk) {
                bf16x8 kf = *(bf16x8*)(Kraw + (((tt * 16 + lr) * 512)
                                | ((((kk * 4 + lg) ^ (lr & 7)) << 4))));
                sv = MFMA16(qf[kk], kf, sv);
            }
            s[tt] = sv;
        }
        // mask (C layout: row = lg*4+r, col = tt*16+lr)
#pragma unroll
        for (int tt = 0; tt < 4; ++tt)
#pragma unroll
            for (int r = 0; r < 4; ++r) {
                bool keep = ((rowbits[r] >> (4 * tt)) & 1ull) != 0;
                s[tt][r] = keep ? s[tt][r] : -1e30f;
            }

        // block row-max over 64 cols
        float bm[4];
#pragma unroll
        for (int r = 0; r < 4; ++r)
            bm[r] = fmaxf(fmaxf(s[0][r], s[1][r]), fmaxf(s[2][r], s[3][r]));
#pragma unroll
        for (int off = 1; off < 16; off <<= 1)
#pragma unroll
            for (int r = 0; r < 4; ++r)
                bm[r] = fmaxf(bm[r], __shfl_xor(bm[r], off));

        // defer-max: rescale only when running max grows by > 8
        bool need = false;
#pragma unroll
        for (int r = 0; r < 4; ++r) need = need || (bm[r] > mrow[r] + 8.f);
        if (__any(need)) {
#pragma unroll
            for (int r = 0; r < 4; ++r) {
                float mn = fmaxf(mrow[r], bm[r]);
                float fr = __expf(mrow[r] - mn);
                mrow[r] = mn;
                lacc[r] *= fr;
#pragma unroll
                for (int dt = 0; dt < 16; ++dt) acc[dt][r] *= fr;
            }
        }

        // ---- P = exp(S - m) -> swizzled LDS (wave-private rows)
#pragma unroll
        for (int tt = 0; tt < 4; ++tt)
#pragma unroll
            for (int r = 0; r < 4; ++r) {
                int prow = w * 16 + lg * 4 + r;
                *(bf16_t*)(Praw + ((prow * 128 + (tt * 16 + lr) * 2)
                                   ^ ((prow & 7) << 4)))
                    = (bf16_t)__expf(s[tt][r] - mrow[r]);
            }
        asm volatile("s_waitcnt lgkmcnt(0)" ::: "memory");
        __builtin_amdgcn_sched_barrier(0);

        // ---- PV (+ row-sum via ones-MFMA); P row = w*16+lr, row&7 = lr&7
        bf16x8 pa0, pa1;
        {
            int prow = w * 16 + lr;
            pa0 = *(bf16x8*)(Praw + ((prow * 128 + (0 * 4 + lg) * 16)
                                     ^ ((prow & 7) << 4)));
            pa1 = *(bf16x8*)(Praw + ((prow * 128 + (1 * 4 + lg) * 16)
                                     ^ ((prow & 7) << 4)));
        }
        lacc = MFMA16(pa0, vone, lacc);
        lacc = MFMA16(pa1, vone, lacc);
#pragma unroll
        for (int dt = 0; dt < 16; ++dt) {
            int vrow = dt * 16 + lr;                   // row&7 = lr&7
            bf16x8 v0 = *(bf16x8*)(Vraw + ((vrow * 128)
                            | ((((0 * 4 + lg) ^ (lr & 7)) << 4))));
            bf16x8 v1 = *(bf16x8*)(Vraw + ((vrow * 128)
                            | ((((1 * 4 + lg) ^ (lr & 7)) << 4))));
            acc[dt] = MFMA16(pa0, v0, acc[dt]);
            acc[dt] = MFMA16(pa1, v1, acc[dt]);
        }
        __syncthreads();   // barrier 2: all LDS reads done before next staging
    }

    if (SPLIT) {
        float* pa = pacc + (size_t)half * 16384 * 256;
#pragma unroll
        for (int r = 0; r < 4; ++r) {
            int row = qw + lg * 4 + r;
#pragma unroll
            for (int dt = 0; dt < 16; ++dt)
                pa[(size_t)row * 256 + dt * 16 + lr] = acc[dt][r];
            if (lr == 0) {
                pm[half * 16384 + row] = mrow[r];
                pl[half * 16384 + row] = lacc[r];
            }
        }
    } else {
#pragma unroll
        for (int r = 0; r < 4; ++r) {
            float inv = 1.0f / lacc[r];
#pragma unroll
            for (int dt = 0; dt < 16; ++dt)
                out[(size_t)(qw + lg * 4 + r) * 256 + dt * 16 + lr] = acc[dt][r] * inv;
        }
    }
}

// ---------------------------------------------------------------------------
// Combine the two kv-split partials.
// ---------------------------------------------------------------------------
__global__ __launch_bounds__(256)
void combine_kernel(const float* __restrict__ pacc, const float* __restrict__ pm,
                    const float* __restrict__ pl, float* __restrict__ out)
{
    int idx = blockIdx.x * 256 + threadIdx.x;
    int row = idx >> 6, c4 = (idx & 63) * 4;
    float m0 = pm[row], m1 = pm[16384 + row];
    float l0 = pl[row], l1 = pl[16384 + row];
    float m  = fmaxf(m0, m1);
    float a  = __expf(m0 - m), b = __expf(m1 - m);
    float inv = 1.0f / (l0 * a + l1 * b);
    float4 x0 = *(const float4*)(pacc + (size_t)row * 256 + c4);
    float4 x1 = *(const float4*)(pacc + (size_t)16384 * 256 + (size_t)row * 256 + c4);
    float4 o;
    o.x = (x0.x * a + x1.x * b) * inv;
    o.y = (x0.y * a + x1.y * b) * inv;
    o.z = (x0.z * a + x1.z * b) * inv;
    o.w = (x0.w * a + x1.w * b) * inv;
    *(float4*)(out + (size_t)row * 256 + c4) = o;
}

// ---------------------------------------------------------------------------
extern "C" void kernel_launch(void* const* d_in, const int* in_sizes, int n_in,
                              void* d_out, int out_size, void* d_ws, size_t ws_size,
                              hipStream_t stream)
{
    const float* gE   = (const float*)d_in[0];
    const float* sE   = (const float*)d_in[1];
    const float* wgt  = (const float*)d_in[2];
    const int*   mask = (const int*)  d_in[3];
    const float* Wq   = (const float*)d_in[4];
    const float* bq   = (const float*)d_in[5];
    const float* Wk   = (const float*)d_in[6];
    const float* bk   = (const float*)d_in[7];
    float* out = (float*)d_out;

    char* ws = (char*)d_ws;
    bf16_t* Qb = (bf16_t*)ws;                              //  8 MB @ 0
    bf16_t* Kb = (bf16_t*)(ws + 8388608);                  //  2 MB (pre-swz)
    bf16_t* VT = (bf16_t*)(ws + 10485760);                 //  2 MB (pre-swz)
    float*  pacc = (float*)(ws + 12582912);                // 32 MB (2 splits)
    float*  pm   = (float*)(ws + 46137344);                // 128 KB
    float*  pl   = (float*)(ws + 46268416);                // 128 KB
    const size_t need_full = 46399488;
    const size_t need_min  = 12582912;

    if (ws_size < need_min) return;

    proj_kernel<512, false><<<dim3(256, 1), 256, 0, stream>>>(gE, Wq, bq, Qb, 0.0625f);
    proj_kernel<256, true ><<<dim3(64, 1), 256, 0, stream>>>(sE, Wk, bk, Kb, 1.0f);
    buildvt_kernel<<<4096, 256, 0, stream>>>(sE, wgt, VT);

    if (ws_size >= need_full) {
        attn_kernel<true><<<dim3(256, 2), 256, 0, stream>>>(
            Qb, Kb, VT, mask, out, pacc, pm, pl);
        combine_kernel<<<4096, 256, 0, stream>>>(pacc, pm, pl, out);
    } else {
        attn_kernel<false><<<dim3(256, 1), 256, 0, stream>>>(
            Qb, Kb, VT, mask, out, nullptr, nullptr, nullptr);
    }
}

// Round 13
// 206.996 us; speedup vs baseline: 4.4206x; 1.0171x over previous
//
#include <hip/hip_runtime.h>
#include <hip/hip_bf16.h>

typedef __bf16 bf16_t;
typedef bf16_t bf16x8 __attribute__((ext_vector_type(8)));
typedef float  f32x4  __attribute__((ext_vector_type(4)));
typedef unsigned long long u64;
typedef unsigned int u32;

#define MFMA16(A,B,C) __builtin_amdgcn_mfma_f32_16x16x32_bf16((A),(B),(C),0,0,0)

// NQ=16384, NK=4096, QDIM=512, KDIM=256, MID=256

// async global -> LDS, 16B per lane; LDS dest = wave-uniform base + lane*16.
static __device__ __forceinline__ void gl_lds16(const bf16_t* g, void* l) {
    __builtin_amdgcn_global_load_lds(
        (const __attribute__((address_space(1))) u32*)(const void*)g,
        (__attribute__((address_space(3))) u32*)l, 16, 0, 0);
}

// ---------------------------------------------------------------------------
// C_bf16[M][256] = (A_f32[M][KA] @ W_f32[256][KA]^T + b[256]) * scale
// SWZ: 16B chunk c of row stored at c ^ (row&7)  (verified r9/r10/r12)
// ---------------------------------------------------------------------------
template<int KA, bool SWZ>
__global__ __launch_bounds__(256)
void proj_kernel(const float* __restrict__ A, const float* __restrict__ W,
                 const float* __restrict__ b, bf16_t* __restrict__ C,
                 float scale)
{
    __shared__ bf16_t Alds[64][40];
    __shared__ bf16_t Wlds[256][40];

    const int t  = threadIdx.x;
    const int w  = t >> 6, l = t & 63, lr = l & 15, lg = l >> 4;
    const int m0 = blockIdx.x * 64;

    f32x4 acc[16];
#pragma unroll
    for (int tt = 0; tt < 16; ++tt) acc[tt] = (f32x4){0.f, 0.f, 0.f, 0.f};

    const int ar  = t >> 2;
    const int ac8 = (t & 3) * 8;

    for (int kb = 0; kb < KA / 32; ++kb) {
        {
            const float* ap = A + (size_t)(m0 + ar) * KA + kb * 32 + ac8;
            float4 a0 = *(const float4*)ap;
            float4 a1 = *(const float4*)(ap + 4);
            bf16x8 av;
            av[0]=(bf16_t)a0.x; av[1]=(bf16_t)a0.y; av[2]=(bf16_t)a0.z; av[3]=(bf16_t)a0.w;
            av[4]=(bf16_t)a1.x; av[5]=(bf16_t)a1.y; av[6]=(bf16_t)a1.z; av[7]=(bf16_t)a1.w;
            *(bf16x8*)&Alds[ar][ac8] = av;
        }
#pragma unroll
        for (int c = 0; c < 4; ++c) {
            int e8 = c * 256 + t;
            int wr = e8 >> 2, wc8 = (e8 & 3) * 8;
            const float* wp = W + (size_t)wr * KA + kb * 32 + wc8;
            float4 w0 = *(const float4*)wp;
            float4 w1 = *(const float4*)(wp + 4);
            bf16x8 wv;
            wv[0]=(bf16_t)w0.x; wv[1]=(bf16_t)w0.y; wv[2]=(bf16_t)w0.z; wv[3]=(bf16_t)w0.w;
            wv[4]=(bf16_t)w1.x; wv[5]=(bf16_t)w1.y; wv[6]=(bf16_t)w1.z; wv[7]=(bf16_t)w1.w;
            *(bf16x8*)&Wlds[wr][wc8] = wv;
        }
        __syncthreads();

        bf16x8 af = *(bf16x8*)&Alds[w * 16 + lr][lg * 8];
#pragma unroll
        for (int tt = 0; tt < 16; ++tt) {
            bf16x8 bfrag = *(bf16x8*)&Wlds[tt * 16 + lr][lg * 8];
            acc[tt] = MFMA16(af, bfrag, acc[tt]);
        }
        __syncthreads();
    }

#pragma unroll
    for (int tt = 0; tt < 16; ++tt) {
        int col = tt * 16 + lr;
        float bias = b[col];
#pragma unroll
        for (int r = 0; r < 4; ++r) {
            int row = m0 + w * 16 + lg * 4 + r;
            int colS = col;
            if (SWZ) colS = (((col >> 3) ^ (row & 7)) << 3) | (col & 7);
            C[(size_t)row * 256 + colS] = (bf16_t)((acc[tt][r] + bias) * scale);
        }
    }
}

// ---------------------------------------------------------------------------
// VT[256][4096] bf16, pre-swizzled within 64-col groups (verified r9/r12):
// VT[d][g*64 + c*8 + j] holds w*S for k = g*64 + (c^(d&7))*8 + j
// ---------------------------------------------------------------------------
__global__ __launch_bounds__(256)
void buildvt_kernel(const float* __restrict__ S, const float* __restrict__ wgt,
                    bf16_t* __restrict__ VT)
{
    int i = blockIdx.x * 256 + threadIdx.x;
    int d = i >> 12, k = i & 4095;
    int kt = (k & ~63) | (((((k >> 3) & 7) ^ (d & 7)) << 3)) | (k & 7);
    VT[i] = (bf16_t)(wgt[kt] * S[(size_t)kt * 256 + d]);
}

// ---------------------------------------------------------------------------
// Flash attention, T3 2-phase pipeline:
//   512 threads = 8 waves x 16 q-rows = 128 q/block; 1 block/CU (144KB LDS);
//   K/V double-buffered: iteration issues async stage of tile t+1 into the
//   other buffer BEFORE computing tile t; ONE __syncthreads per tile (its
//   vmcnt drain lands after ~3.5k cycles of compute -> latency hidden).
//   Kb/VT pre-swizzled in global (conflict-free staged + XOR reads);
//   mask via __ballot (SGPR); denominator via ones-MFMA.  grid (128, SPLIT+1).
// ---------------------------------------------------------------------------
template<bool SPLIT>
__global__ __launch_bounds__(512, 2)
void attn_kernel(const bf16_t* __restrict__ Qb, const bf16_t* __restrict__ Kb,
                 const bf16_t* __restrict__ VT, const int* __restrict__ mask,
                 float* __restrict__ out, float* __restrict__ pacc,
                 float* __restrict__ pm, float* __restrict__ pl)
{
    __shared__ __align__(16) char Kraw[2][32768];  // K  [64][256] (pre-swz)
    __shared__ __align__(16) char Vraw[2][32768];  // VT [256][64] (pre-swz)
    __shared__ __align__(16) char Praw[16384];     // P  [128][64] swz

    const int t  = threadIdx.x;
    const int w  = t >> 6, l = t & 63, lr = l & 15, lg = l >> 4;
    const int qw = blockIdx.x * 128 + w * 16;      // wave's 16 q-rows
    const int half = SPLIT ? (int)blockIdx.y : 0;
    const int NT   = SPLIT ? 32 : 64;
    const int kb0  = half * NT;

    // hoist Q fragments (A-frag: row = lr, k = kk*32 + lg*8 + j)
    bf16x8 qf[8];
    {
        const bf16_t* qrow = Qb + (size_t)(qw + lr) * 256;
#pragma unroll
        for (int kk = 0; kk < 8; ++kk)
            qf[kk] = *(const bf16x8*)(qrow + kk * 32 + lg * 8);
    }

    bf16x8 vone;
#pragma unroll
    for (int j = 0; j < 8; ++j) vone[j] = (bf16_t)1.0f;

    f32x4 acc[16];
#pragma unroll
    for (int dt = 0; dt < 16; ++dt) acc[dt] = (f32x4){0.f, 0.f, 0.f, 0.f};
    f32x4 lacc = (f32x4){0.f, 0.f, 0.f, 0.f};   // row-sum accumulator (P @ 1)
    float mrow[4];
#pragma unroll
    for (int r = 0; r < 4; ++r) mrow[r] = -1e30f;

    // ---- async stage of one 64-kv tile, split across 8 waves
    auto stage = [&](int kb, char* kd, char* vd) {
#pragma unroll
        for (int i = 0; i < 4; ++i) {          // K: wave w -> rows w*8..+7
            int row = w * 8 + i * 2 + (l >> 5);
            gl_lds16(Kb + (size_t)(kb * 64 + row) * 256 + (l & 31) * 8,
                     kd + (w * 8 + i * 2) * 512);
        }
#pragma unroll
        for (int i = 0; i < 4; ++i) {          // VT: wave w -> d = w*32..+31
            int d = w * 32 + i * 8 + (l >> 3);
            gl_lds16(VT + (size_t)d * 4096 + kb * 64 + (l & 7) * 8,
                     vd + (w * 32 + i * 8) * 128);
        }
    };

    auto iter = [&](int kb, char* kcur, char* vcur, char* knxt, char* vnxt,
                    bool do_stage) {
        // ---- mask loads FIRST (older in vmcnt FIFO than staging)
        int4 mv[4];
#pragma unroll
        for (int r = 0; r < 4; ++r)
            mv[r] = *(const int4*)(mask + (size_t)(qw + 4 * lg + r) * 4096
                                   + kb * 64 + lr * 4);

        // ---- issue NEXT tile's staging (async, other buffer)
        if (do_stage) stage(kb + 1, knxt, vnxt);

        // ---- mask via ballot (SGPR path; waits only on mask loads)
        u64 rowbits[4];
#pragma unroll
        for (int r = 0; r < 4; ++r) {
            u64 b0 = __ballot(mv[r].x != 0);
            u64 b1 = __ballot(mv[r].y != 0);
            u64 b2 = __ballot(mv[r].z != 0);
            u64 b3 = __ballot(mv[r].w != 0);
            u64 w01  = (lr & 1) ? b1 : b0;
            u64 w23  = (lr & 1) ? b3 : b2;
            u64 wsel = (lr & 2) ? w23 : w01;
            rowbits[r] = wsel >> (lg * 16 + (lr >> 2));  // bit 4*tt = keep
        }

        // ---- S = Q K^T from current buffer
        f32x4 s[4];
#pragma unroll
        for (int tt = 0; tt < 4; ++tt) {
            f32x4 sv = (f32x4){0.f, 0.f, 0.f, 0.f};
#pragma unroll
            for (int kk = 0; kk < 8; ++kk) {
                bf16x8 kf = *(bf16x8*)(kcur + (((tt * 16 + lr) * 512)
                                | ((((kk * 4 + lg) ^ (lr & 7)) << 4))));
                sv = MFMA16(qf[kk], kf, sv);
            }
            s[tt] = sv;
        }
        // mask (C layout: row = lg*4+r, col = tt*16+lr)
#pragma unroll
        for (int tt = 0; tt < 4; ++tt)
#pragma unroll
            for (int r = 0; r < 4; ++r) {
                bool keep = ((rowbits[r] >> (4 * tt)) & 1ull) != 0;
                s[tt][r] = keep ? s[tt][r] : -1e30f;
            }

        // block row-max over 64 cols
        float bm[4];
#pragma unroll
        for (int r = 0; r < 4; ++r)
            bm[r] = fmaxf(fmaxf(s[0][r], s[1][r]), fmaxf(s[2][r], s[3][r]));
#pragma unroll
        for (int off = 1; off < 16; off <<= 1)
#pragma unroll
            for (int r = 0; r < 4; ++r)
                bm[r] = fmaxf(bm[r], __shfl_xor(bm[r], off));

        // defer-max: rescale only when running max grows by > 8
        bool need = false;
#pragma unroll
        for (int r = 0; r < 4; ++r) need = need || (bm[r] > mrow[r] + 8.f);
        if (__any(need)) {
#pragma unroll
            for (int r = 0; r < 4; ++r) {
                float mn = fmaxf(mrow[r], bm[r]);
                float fr = __expf(mrow[r] - mn);
                mrow[r] = mn;
                lacc[r] *= fr;
#pragma unroll
                for (int dt = 0; dt < 16; ++dt) acc[dt][r] *= fr;
            }
        }

        // ---- P = exp(S - m) -> swizzled LDS (wave-private rows)
#pragma unroll
        for (int tt = 0; tt < 4; ++tt)
#pragma unroll
            for (int r = 0; r < 4; ++r) {
                int prow = w * 16 + lg * 4 + r;
                *(bf16_t*)(Praw + ((prow * 128 + (tt * 16 + lr) * 2)
                                   ^ ((prow & 7) << 4)))
                    = (bf16_t)__expf(s[tt][r] - mrow[r]);
            }
        asm volatile("s_waitcnt lgkmcnt(0)" ::: "memory");
        __builtin_amdgcn_sched_barrier(0);

        // ---- PV (+ row-sum via ones-MFMA)
        bf16x8 pa0, pa1;
        {
            int prow = w * 16 + lr;
            pa0 = *(bf16x8*)(Praw + ((prow * 128 + (0 * 4 + lg) * 16)
                                     ^ ((prow & 7) << 4)));
            pa1 = *(bf16x8*)(Praw + ((prow * 128 + (1 * 4 + lg) * 16)
                                     ^ ((prow & 7) << 4)));
        }
        lacc = MFMA16(pa0, vone, lacc);
        lacc = MFMA16(pa1, vone, lacc);
#pragma unroll
        for (int dt = 0; dt < 16; ++dt) {
            int vrow = dt * 16 + lr;                   // row&7 = lr&7
            bf16x8 v0 = *(bf16x8*)(vcur + ((vrow * 128)
                            | ((((0 * 4 + lg) ^ (lr & 7)) << 4))));
            bf16x8 v1 = *(bf16x8*)(vcur + ((vrow * 128)
                            | ((((1 * 4 + lg) ^ (lr & 7)) << 4))));
            acc[dt] = MFMA16(pa0, v0, acc[dt]);
            acc[dt] = MFMA16(pa1, v1, acc[dt]);
        }
        // ONE barrier per tile: drains staging vmcnt (next buffer ready)
        // AND guarantees all reads of the current buffer completed.
        __syncthreads();
    };

    // ---- prologue: stage tile kb0 into buffer 0
    stage(kb0, &Kraw[0][0], &Vraw[0][0]);
    __syncthreads();

    for (int tb = 0; tb < NT; tb += 2) {
        iter(kb0 + tb,     &Kraw[0][0], &Vraw[0][0], &Kraw[1][0], &Vraw[1][0],
             true);
        iter(kb0 + tb + 1, &Kraw[1][0], &Vraw[1][0], &Kraw[0][0], &Vraw[0][0],
             tb + 2 < NT);
    }

    if (SPLIT) {
        float* pa = pacc + (size_t)half * 16384 * 256;
#pragma unroll
        for (int r = 0; r < 4; ++r) {
            int row = qw + lg * 4 + r;
#pragma unroll
            for (int dt = 0; dt < 16; ++dt)
                pa[(size_t)row * 256 + dt * 16 + lr] = acc[dt][r];
            if (lr == 0) {
                pm[half * 16384 + row] = mrow[r];
                pl[half * 16384 + row] = lacc[r];
            }
        }
    } else {
#pragma unroll
        for (int r = 0; r < 4; ++r) {
            float inv = 1.0f / lacc[r];
#pragma unroll
            for (int dt = 0; dt < 16; ++dt)
                out[(size_t)(qw + lg * 4 + r) * 256 + dt * 16 + lr] = acc[dt][r] * inv;
        }
    }
}

// ---------------------------------------------------------------------------
// Combine the two kv-split partials.
// ---------------------------------------------------------------------------
__global__ __launch_bounds__(256)
void combine_kernel(const float* __restrict__ pacc, const float* __restrict__ pm,
                    const float* __restrict__ pl, float* __restrict__ out)
{
    int idx = blockIdx.x * 256 + threadIdx.x;
    int row = idx >> 6, c4 = (idx & 63) * 4;
    float m0 = pm[row], m1 = pm[16384 + row];
    float l0 = pl[row], l1 = pl[16384 + row];
    float m  = fmaxf(m0, m1);
    float a  = __expf(m0 - m), b = __expf(m1 - m);
    float inv = 1.0f / (l0 * a + l1 * b);
    float4 x0 = *(const float4*)(pacc + (size_t)row * 256 + c4);
    float4 x1 = *(const float4*)(pacc + (size_t)16384 * 256 + (size_t)row * 256 + c4);
    float4 o;
    o.x = (x0.x * a + x1.x * b) * inv;
    o.y = (x0.y * a + x1.y * b) * inv;
    o.z = (x0.z * a + x1.z * b) * inv;
    o.w = (x0.w * a + x1.w * b) * inv;
    *(float4*)(out + (size_t)row * 256 + c4) = o;
}

// ---------------------------------------------------------------------------
extern "C" void kernel_launch(void* const* d_in, const int* in_sizes, int n_in,
                              void* d_out, int out_size, void* d_ws, size_t ws_size,
                              hipStream_t stream)
{
    const float* gE   = (const float*)d_in[0];
    const float* sE   = (const float*)d_in[1];
    const float* wgt  = (const float*)d_in[2];
    const int*   mask = (const int*)  d_in[3];
    const float* Wq   = (const float*)d_in[4];
    const float* bq   = (const float*)d_in[5];
    const float* Wk   = (const float*)d_in[6];
    const float* bk   = (const float*)d_in[7];
    float* out = (float*)d_out;

    char* ws = (char*)d_ws;
    bf16_t* Qb = (bf16_t*)ws;                              //  8 MB @ 0
    bf16_t* Kb = (bf16_t*)(ws + 8388608);                  //  2 MB (pre-swz)
    bf16_t* VT = (bf16_t*)(ws + 10485760);                 //  2 MB (pre-swz)
    float*  pacc = (float*)(ws + 12582912);                // 32 MB (2 splits)
    float*  pm   = (float*)(ws + 46137344);                // 128 KB
    float*  pl   = (float*)(ws + 46268416);                // 128 KB
    const size_t need_full = 46399488;
    const size_t need_min  = 12582912;

    if (ws_size < need_min) return;

    proj_kernel<512, false><<<dim3(256, 1), 256, 0, stream>>>(gE, Wq, bq, Qb, 0.0625f);
    proj_kernel<256, true ><<<dim3(64, 1), 256, 0, stream>>>(sE, Wk, bk, Kb, 1.0f);
    buildvt_kernel<<<4096, 256, 0, stream>>>(sE, wgt, VT);

    if (ws_size >= need_full) {
        attn_kernel<true><<<dim3(128, 2), 512, 0, stream>>>(
            Qb, Kb, VT, mask, out, pacc, pm, pl);
        combine_kernel<<<4096, 256, 0, stream>>>(pacc, pm, pl, out);
    } else {
        attn_kernel<false><<<dim3(128, 1), 512, 0, stream>>>(
            Qb, Kb, VT, mask, out, nullptr, nullptr, nullptr);
    }
}